// Round 1
// baseline (231.853 us; speedup 1.0000x reference)
//
#include <hip/hip_runtime.h>
#include <hip/hip_cooperative_groups.h>
#include <math.h>

namespace cg = cooperative_groups;

#define EPS32 1.1920929e-07f

constexpr int B = 16, C = 80, H = 128, W = 128, NBOX = 64;
constexpr int NBLK = B * NBOX;        // 1024 blocks: one box each + streaming slice
constexpr int NTOT = B * C * H * W;   // 20,971,520
constexpr int NV4  = NTOT / 4;        // 5,242,880 float4s
constexpr int SSTRIDE = NBLK * 256;   // 262,144 -> exactly 20 float4 iters/thread
constexpr int SITER = NV4 / SSTRIDE;  // 20
static_assert(SITER * SSTRIDE == NV4, "streaming must tile exactly");

__device__ __forceinline__ float f0_term(float p) {
    // ct == 0 branch of the focal loss: -log(1-p+1e-12) * p^2
    return -__logf(1.0f - p + 1e-12f) * p * p;
}

// Block-wide sum; result valid on thread 0 only. Contains one __syncthreads.
__device__ __forceinline__ float block_reduce_add(float v, float* sred) {
    #pragma unroll
    for (int off = 32; off > 0; off >>= 1)
        v += __shfl_down(v, off, 64);
    int lane = threadIdx.x & 63;
    int wid  = threadIdx.x >> 6;
    if (lane == 0) sred[wid] = v;
    __syncthreads();
    if (threadIdx.x == 0) {
        float s = sred[0];
        #pragma unroll
        for (int i = 1; i < 4; ++i) s += sred[i];
        return s;
    }
    return 0.0f;
}

// Per-block partial {center, wh, offset, af}; valid on thread 0 only.
// Block k handles box (b = k>>6, n = k&63) correction + a 1/1024 streaming slice.
__device__ __forceinline__ float4 block_partial(
    const float* __restrict__ cp, const float* __restrict__ whp,
    const float* __restrict__ ofp, const float* __restrict__ boxes,
    const int* __restrict__ labels, float* sred)
{
    __shared__ int   scx[NBOX], scy[NBOX], sre[NBOX], slab[NBOX];
    __shared__ float sinv[NBOX];
    __shared__ unsigned long long cand_mask;   // same-batch same-label boxes
    __shared__ float s_woa[3];                 // {wh, offset, af} from thread n
    const int t = threadIdx.x;
    const int k = blockIdx.x;
    const int b = k >> 6;
    const int n = k & 63;

    float sw_t = 0.0f, sh_t = 0.0f, ox_t = 0.0f, oy_t = 0.0f;
    if (t < NBOX) {
        const float* bx = boxes + ((b * NBOX + t) << 2);
        float x1 = bx[0], y1 = bx[1], x2 = bx[2], y2 = bx[3];
        // w_ratio = h_ratio = 128/512 = 0.25 (exact power-of-2 scalings)
        float cx = (x1 + x2) * 0.25f * 0.5f;
        float cy = (y1 + y2) * 0.25f * 0.5f;
        int cxi = (int)floorf(cx);
        int cyi = (int)floorf(cy);
        float sw = (x2 - x1) * 0.25f;
        float sh = (y2 - y1) * 0.25f;
        // gaussian radius, min_overlap = 0.3 (h = sh, w = sw)
        float h = sh, w = sw;
        float b1 = h + w;
        float c1 = w * h * 0.7f / 1.3f;
        float r1 = (b1 - sqrtf(b1 * b1 - 4.0f * c1)) * 0.5f;
        float b2 = 2.0f * (h + w);
        float c2 = 0.7f * w * h;
        float r2 = (b2 - sqrtf(b2 * b2 - 16.0f * c2)) * 0.125f;
        float b3 = -0.6f * (h + w);
        float c3 = -0.7f * w * h;
        float r3 = (b3 + sqrtf(b3 * b3 - 4.8f * c3)) / 2.4f;
        float r = fminf(fminf(r1, r2), r3);
        int rad = (int)fmaxf(0.0f, floorf(r));
        float d = (float)(2 * rad + 1);
        float sigma2 = 2.0f * d / 6.0f * (d / 6.0f);
        scx[t] = cxi; scy[t] = cyi;
        sre[t] = rad < 16 ? rad : 16;     // window clamp (reference grid is +-16)
        slab[t] = labels[b * NBOX + t];
        sinv[t] = 1.0f / sigma2;
        sw_t = sw; sh_t = sh;
        ox_t = cx - (float)cxi; oy_t = cy - (float)cyi;
        if (t == 0) { s_woa[0] = 0.0f; s_woa[1] = 0.0f; s_woa[2] = 0.0f; }
    }
    __syncthreads();

    // Wave-0 ballots replace the old serial thread-0 list building (~128 iters).
    if (t < NBOX) {
        const int cxn = scx[n], cyn = scy[n], labn = slab[n];
        bool same_cell = (scx[t] == cxn) && (scy[t] == cyn);
        // wh/offset scatter-set => last write (max index) wins per (cyi,cxi)
        unsigned long long clash = __ballot(same_cell && (t > n));
        // af counts distinct (label, cyi, cxi) => first occurrence
        unsigned long long firstm = __ballot(same_cell && (slab[t] == labn) && (t < n));
        // candidate set for the gaussian max: same-batch same-label boxes
        unsigned long long cand = __ballot(slab[t] == labn);
        if (t == n) {
            cand_mask = cand;
            if (clash == 0ULL) {
                int i0 = ((b * 2 + 0) * H + cyn) * W + cxn;
                int i1 = ((b * 2 + 1) * H + cyn) * W + cxn;
                s_woa[0] = fabsf(whp[i0] - sw_t) + fabsf(whp[i1] - sh_t);
                s_woa[1] = fabsf(ofp[i0] - ox_t) + fabsf(ofp[i1] - oy_t);
            }
            if (firstm == 0ULL) s_woa[2] = 1.0f;
        }
    }

    // ---------- dense streaming slice: sum f0 over 20 float4s/thread ----------
    const float4* cp4 = (const float4*)cp;
    const int base = k * 256 + t;
    float s0 = 0.0f, s1 = 0.0f, s2 = 0.0f, s3 = 0.0f;
    #pragma unroll 1
    for (int j = 0; j < SITER; j += 4) {
        float4 a = cp4[base + (j + 0) * SSTRIDE];
        float4 bb = cp4[base + (j + 1) * SSTRIDE];
        float4 c = cp4[base + (j + 2) * SSTRIDE];
        float4 dd = cp4[base + (j + 3) * SSTRIDE];
        s0 += f0_term(a.x) + f0_term(a.y) + f0_term(a.z) + f0_term(a.w);
        s1 += f0_term(bb.x) + f0_term(bb.y) + f0_term(bb.z) + f0_term(bb.w);
        s2 += f0_term(c.x) + f0_term(c.y) + f0_term(c.z) + f0_term(c.w);
        s3 += f0_term(dd.x) + f0_term(dd.y) + f0_term(dd.z) + f0_term(dd.w);
    }
    float center = (s0 + s1) + (s2 + s3);

    __syncthreads();   // cand_mask / s_woa visible to all

    // ---------- sparse correction: this block's box window ----------
    const int c   = slab[n];
    const int R   = sre[n];
    const int Wd  = 2 * R + 1;
    const int cells = Wd * Wd;
    const int cx0 = scx[n], cy0 = scy[n];
    const unsigned long long cmask = cand_mask;
    float corr = 0.0f;
    for (int cell = t; cell < cells; cell += 256) {
        int dy = cell / Wd - R;
        int dx = cell - (dy + R) * Wd - R;
        int y = cy0 + dy, x = cx0 + dx;
        if ((unsigned)y >= (unsigned)H || (unsigned)x >= (unsigned)W) continue;
        // ct = max gaussian over covering same-label boxes; owner = min index
        int minm = NBOX;
        float ct = 0.0f;
        unsigned long long mm = cmask;
        while (mm) {
            int m = __ffsll(mm) - 1;
            mm &= mm - 1;
            int ddx = x - scx[m], ddy = y - scy[m];
            int re = sre[m];
            if (ddx > re || ddx < -re || ddy > re || ddy < -re) continue;
            if (m < minm) minm = m;
            float d2 = (float)(ddx * ddx + ddy * ddy);
            float kv = (d2 == 0.0f) ? 1.0f : __expf(-d2 * sinv[m]);
            if (kv < EPS32) kv = 0.0f;          // reference EPS cut
            ct = fmaxf(ct, kv);
        }
        if (minm != n) continue;                 // another block owns this cell
        float p = cp[((b * C + c) * H + y) * W + x];
        float lt = __logf(1.0f - p + 1e-12f);
        float omc = 1.0f - ct;
        float w2 = omc * omc;
        float w4 = w2 * w2;
        // f(p,ct) - f0(p):  neg-weight delta + pos term at exact centers
        float val = -lt * p * p * (w4 - 1.0f);
        if (ct == 1.0f) {
            float q = 1.0f - p;
            val += -__logf(p + 1e-12f) * q * q;
        }
        corr += val;
    }
    center += corr;

    float cs = block_reduce_add(center, sred);   // contains a __syncthreads
    float4 out4 = {0.0f, 0.0f, 0.0f, 0.0f};
    if (t == 0) {
        out4.x = cs;
        out4.y = s_woa[0]; out4.z = s_woa[1]; out4.w = s_woa[2];
    }
    return out4;
}

// ---------- single cooperative kernel: partials + grid sync + finalize ----------
__global__ __launch_bounds__(256, 4) void fused_coop(
    const float* __restrict__ cp, const float* __restrict__ whp,
    const float* __restrict__ ofp, const float* __restrict__ boxes,
    const int* __restrict__ labels, float4* __restrict__ ws4,
    float* __restrict__ out)
{
    __shared__ float sred[4];
    float4 p = block_partial(cp, whp, ofp, boxes, labels, sred);
    if (threadIdx.x == 0) ws4[blockIdx.x] = p;
    cg::this_grid().sync();
    if (blockIdx.x == 0) {
        float c = 0.0f, wh = 0.0f, of = 0.0f, af = 0.0f;
        for (int i = threadIdx.x; i < NBLK; i += 256) {
            float4 v = ws4[i];
            c += v.x; wh += v.y; of += v.z; af += v.w;
        }
        float cs = block_reduce_add(c, sred);  __syncthreads();
        float ws = block_reduce_add(wh, sred); __syncthreads();
        float os = block_reduce_add(of, sred); __syncthreads();
        float as = block_reduce_add(af, sred);
        if (threadIdx.x == 0) {
            float a = fmaxf(1.0f, as);
            out[0] = cs / (a + EPS32)
                   + 0.1f * ws / (a * 2.0f + EPS32)
                   + os / (a * 2.0f + EPS32);
        }
    }
}

// ---------- fallback: two-kernel path (if coop grid can't co-reside) ----------
__global__ __launch_bounds__(256, 4) void fused_plain(
    const float* __restrict__ cp, const float* __restrict__ whp,
    const float* __restrict__ ofp, const float* __restrict__ boxes,
    const int* __restrict__ labels, float4* __restrict__ ws4)
{
    __shared__ float sred[4];
    float4 p = block_partial(cp, whp, ofp, boxes, labels, sred);
    if (threadIdx.x == 0) ws4[blockIdx.x] = p;
}

__global__ __launch_bounds__(256) void finalize_kernel(
    const float4* __restrict__ ws4, float* __restrict__ out)
{
    __shared__ float sred[4];
    float c = 0.0f, wh = 0.0f, of = 0.0f, af = 0.0f;
    for (int i = threadIdx.x; i < NBLK; i += 256) {
        float4 v = ws4[i];
        c += v.x; wh += v.y; of += v.z; af += v.w;
    }
    float cs = block_reduce_add(c, sred);  __syncthreads();
    float ws = block_reduce_add(wh, sred); __syncthreads();
    float os = block_reduce_add(of, sred); __syncthreads();
    float as = block_reduce_add(af, sred);
    if (threadIdx.x == 0) {
        float a = fmaxf(1.0f, as);
        out[0] = cs / (a + EPS32)
               + 0.1f * ws / (a * 2.0f + EPS32)
               + os / (a * 2.0f + EPS32);
    }
}

extern "C" void kernel_launch(void* const* d_in, const int* in_sizes, int n_in,
                              void* d_out, int out_size, void* d_ws, size_t ws_size,
                              hipStream_t stream) {
    const float* cp     = (const float*)d_in[0];   // center_pred (16,80,128,128)
    const float* whp    = (const float*)d_in[1];   // wh_pred     (16,2,128,128)
    const float* ofp    = (const float*)d_in[2];   // offset_pred (16,2,128,128)
    const float* boxes  = (const float*)d_in[3];   // (16,64,4)
    const int*   labels = (const int*)d_in[4];     // (16,64)
    float4* ws4 = (float4*)d_ws;                   // NBLK float4 partials (16 KB)
    float*  outp = (float*)d_out;

    // Decide once whether the cooperative grid (1024 blocks, 4/CU on 256 CUs)
    // is co-resident; host-side query only, safe under graph capture.
    static int coop = -1;
    if (coop < 0) {
        int maxb = 0;
        hipError_t e = hipOccupancyMaxActiveBlocksPerMultiprocessor(
            &maxb, (const void*)fused_coop, 256, 0);
        coop = (e == hipSuccess && maxb >= 4) ? 1 : 0;
    }

    if (coop) {
        void* args[] = {(void*)&cp, (void*)&whp, (void*)&ofp,
                        (void*)&boxes, (void*)&labels, (void*)&ws4, (void*)&outp};
        hipLaunchCooperativeKernel((const void*)fused_coop, dim3(NBLK), dim3(256),
                                   args, 0, stream);
    } else {
        fused_plain<<<NBLK, 256, 0, stream>>>(cp, whp, ofp, boxes, labels, ws4);
        finalize_kernel<<<1, 256, 0, stream>>>(ws4, outp);
    }
}

// Round 2
// 131.675 us; speedup vs baseline: 1.7608x; 1.7608x over previous
//
#include <hip/hip_runtime.h>
#include <math.h>

#define EPS32 1.1920929e-07f

constexpr int B = 16, C = 80, H = 128, W = 128, NBOX = 64;
constexpr int NCORR = B * NBOX;        // 1024 correction-carrying blocks
constexpr int NBLK  = 2048;            // all blocks stream; 8 blocks/CU, one round
constexpr int NTOT  = B * C * H * W;   // 20,971,520
constexpr int NV4   = NTOT / 4;        // 5,242,880 float4s
constexpr int SSTRIDE = NBLK * 256;    // 524,288 -> exactly 10 float4 iters/thread
constexpr int SITER = NV4 / SSTRIDE;   // 10
static_assert(SITER * SSTRIDE == NV4, "streaming must tile exactly");

__device__ __forceinline__ float f0_term(float p) {
    // ct == 0 branch of the focal loss: -log(1-p+1e-12) * p^2
    return -__logf(1.0f - p + 1e-12f) * p * p;
}

// Block-wide sum; result valid on thread 0 only. Contains one __syncthreads.
__device__ __forceinline__ float block_reduce_add(float v, float* sred) {
    #pragma unroll
    for (int off = 32; off > 0; off >>= 1)
        v += __shfl_down(v, off, 64);
    int lane = threadIdx.x & 63;
    int wid  = threadIdx.x >> 6;
    if (lane == 0) sred[wid] = v;
    __syncthreads();
    if (threadIdx.x == 0) {
        float s = sred[0];
        #pragma unroll
        for (int i = 1; i < 4; ++i) s += sred[i];
        return s;
    }
    return 0.0f;
}

// Each block writes one float4 partial {center, wh, offset, af} to ws4[blockIdx.x].
// Blocks 0..NCORR-1 additionally own box (b = k>>6, n = k&63)'s sparse correction.
// All blocks stream a 1/2048 slice of center_pred (balanced: 10 float4s/thread).
__global__ __launch_bounds__(256) void fused_kernel(
    const float* __restrict__ cp, const float* __restrict__ whp,
    const float* __restrict__ ofp, const float* __restrict__ boxes,
    const int* __restrict__ labels, float4* __restrict__ ws4)
{
    __shared__ float sred[4];
    __shared__ int   scx[NBOX], scy[NBOX], sre[NBOX], slab[NBOX];
    __shared__ float sinv[NBOX];
    __shared__ unsigned long long cand_mask;   // same-batch same-label boxes
    __shared__ float s_woa[3];                 // {wh, offset, af} from thread n
    const int t = threadIdx.x;
    const int k = blockIdx.x;
    const bool has_box = (k < NCORR);
    const int b = (k >> 6) & (B - 1);
    const int n = k & 63;

    if (has_box) {
        // ---------- box setup (wave 0) ----------
        if (t < NBOX) {
            const float* bx = boxes + ((b * NBOX + t) << 2);
            float x1 = bx[0], y1 = bx[1], x2 = bx[2], y2 = bx[3];
            // w_ratio = h_ratio = 128/512 = 0.25 (exact power-of-2 scalings)
            float cx = (x1 + x2) * 0.25f * 0.5f;
            float cy = (y1 + y2) * 0.25f * 0.5f;
            int cxi = (int)floorf(cx);
            int cyi = (int)floorf(cy);
            float sw = (x2 - x1) * 0.25f;
            float sh = (y2 - y1) * 0.25f;
            // gaussian radius, min_overlap = 0.3 (h = sh, w = sw)
            float h = sh, w = sw;
            float b1 = h + w;
            float c1 = w * h * 0.7f / 1.3f;
            float r1 = (b1 - sqrtf(b1 * b1 - 4.0f * c1)) * 0.5f;
            float b2 = 2.0f * (h + w);
            float c2 = 0.7f * w * h;
            float r2 = (b2 - sqrtf(b2 * b2 - 16.0f * c2)) * 0.125f;
            float b3 = -0.6f * (h + w);
            float c3 = -0.7f * w * h;
            float r3 = (b3 + sqrtf(b3 * b3 - 4.8f * c3)) / 2.4f;
            float r = fminf(fminf(r1, r2), r3);
            int rad = (int)fmaxf(0.0f, floorf(r));
            float d = (float)(2 * rad + 1);
            float sigma2 = 2.0f * d / 6.0f * (d / 6.0f);
            scx[t] = cxi; scy[t] = cyi;
            sre[t] = rad < 16 ? rad : 16;     // window clamp (reference grid is +-16)
            slab[t] = labels[b * NBOX + t];
            sinv[t] = 1.0f / sigma2;
            if (t == 0) { s_woa[0] = 0.0f; s_woa[1] = 0.0f; s_woa[2] = 0.0f; }
            // keep per-thread box values for the t==n writes below
            float ox = cx - (float)cxi, oy = cy - (float)cyi;
            __syncthreads();
            // ---------- wave-0 ballots replace serial thread-0 loops ----------
            const int cxn = scx[n], cyn = scy[n], labn = slab[n];
            bool same_cell = (scx[t] == cxn) && (scy[t] == cyn);
            // wh/offset scatter-set => last write (max index) wins per (cyi,cxi)
            unsigned long long clash = __ballot(same_cell && (t > n));
            // af counts distinct (label, cyi, cxi) => first occurrence
            unsigned long long firstm = __ballot(same_cell && (slab[t] == labn) && (t < n));
            // candidate set for the gaussian max: same-batch same-label boxes
            unsigned long long cand = __ballot(slab[t] == labn);
            if (t == n) {
                cand_mask = cand;
                if (clash == 0ULL) {
                    int i0 = ((b * 2 + 0) * H + cyn) * W + cxn;
                    int i1 = ((b * 2 + 1) * H + cyn) * W + cxn;
                    s_woa[0] = fabsf(whp[i0] - sw) + fabsf(whp[i1] - sh);
                    s_woa[1] = fabsf(ofp[i0] - ox) + fabsf(ofp[i1] - oy);
                }
                if (firstm == 0ULL) s_woa[2] = 1.0f;
            }
        } else {
            __syncthreads();   // matches the wave-0 barrier above
        }
    }

    // ---------- dense streaming slice (all blocks): 10 float4s/thread ----------
    const float4* cp4 = (const float4*)cp;
    const int base = k * 256 + t;
    float s0 = 0.0f, s1 = 0.0f;
    #pragma unroll 1
    for (int j = 0; j < SITER; j += 2) {
        float4 a  = cp4[base + (j + 0) * SSTRIDE];
        float4 bb = cp4[base + (j + 1) * SSTRIDE];
        s0 += f0_term(a.x) + f0_term(a.y) + f0_term(a.z) + f0_term(a.w);
        s1 += f0_term(bb.x) + f0_term(bb.y) + f0_term(bb.z) + f0_term(bb.w);
    }
    float center = s0 + s1;

    if (has_box) {
        __syncthreads();   // cand_mask / box LDS visible to all 4 waves

        // ---------- sparse correction: this block's box window ----------
        const int c   = slab[n];
        const int R   = sre[n];
        const int Wd  = 2 * R + 1;
        const int cells = Wd * Wd;
        const int cx0 = scx[n], cy0 = scy[n];
        const unsigned long long cmask = cand_mask;
        float corr = 0.0f;
        for (int cell = t; cell < cells; cell += 256) {
            int dy = cell / Wd - R;
            int dx = cell - (dy + R) * Wd - R;
            int y = cy0 + dy, x = cx0 + dx;
            if ((unsigned)y >= (unsigned)H || (unsigned)x >= (unsigned)W) continue;
            // ct = max gaussian over covering same-label boxes; owner = min index
            int minm = NBOX;
            float ct = 0.0f;
            unsigned long long mm = cmask;
            while (mm) {
                int m = __ffsll(mm) - 1;
                mm &= mm - 1;
                int ddx = x - scx[m], ddy = y - scy[m];
                int re = sre[m];
                if (ddx > re || ddx < -re || ddy > re || ddy < -re) continue;
                if (m < minm) minm = m;
                float d2 = (float)(ddx * ddx + ddy * ddy);
                float kv = (d2 == 0.0f) ? 1.0f : __expf(-d2 * sinv[m]);
                if (kv < EPS32) kv = 0.0f;          // reference EPS cut
                ct = fmaxf(ct, kv);
            }
            if (minm == n) {                         // this block owns the cell
                float p = cp[((b * C + c) * H + y) * W + x];
                float lt = __logf(1.0f - p + 1e-12f);
                float omc = 1.0f - ct;
                float w2 = omc * omc;
                float w4 = w2 * w2;
                // f(p,ct) - f0(p): neg-weight delta + pos term at exact centers
                float val = -lt * p * p * (w4 - 1.0f);
                if (ct == 1.0f) {
                    float q = 1.0f - p;
                    val += -__logf(p + 1e-12f) * q * q;
                }
                corr += val;
            }
        }
        center += corr;
    }

    float cs = block_reduce_add(center, sred);   // contains a __syncthreads
    if (t == 0) {
        float4 out;
        out.x = cs;
        if (has_box) { out.y = s_woa[0]; out.z = s_woa[1]; out.w = s_woa[2]; }
        else         { out.y = 0.0f;     out.z = 0.0f;     out.w = 0.0f;     }
        ws4[k] = out;
    }
}

__global__ __launch_bounds__(256) void finalize_kernel(
    const float4* __restrict__ ws4, float* __restrict__ out)
{
    __shared__ float sred[4];
    float c = 0.0f, wh = 0.0f, of = 0.0f, af = 0.0f;
    for (int i = threadIdx.x; i < NBLK; i += 256) {
        float4 v = ws4[i];
        c += v.x; wh += v.y; of += v.z; af += v.w;
    }
    float cs = block_reduce_add(c, sred);  __syncthreads();
    float ws = block_reduce_add(wh, sred); __syncthreads();
    float os = block_reduce_add(of, sred); __syncthreads();
    float as = block_reduce_add(af, sred);
    if (threadIdx.x == 0) {
        float a = fmaxf(1.0f, as);
        out[0] = cs / (a + EPS32)
               + 0.1f * ws / (a * 2.0f + EPS32)
               + os / (a * 2.0f + EPS32);
    }
}

extern "C" void kernel_launch(void* const* d_in, const int* in_sizes, int n_in,
                              void* d_out, int out_size, void* d_ws, size_t ws_size,
                              hipStream_t stream) {
    const float* cp     = (const float*)d_in[0];   // center_pred (16,80,128,128)
    const float* whp    = (const float*)d_in[1];   // wh_pred     (16,2,128,128)
    const float* ofp    = (const float*)d_in[2];   // offset_pred (16,2,128,128)
    const float* boxes  = (const float*)d_in[3];   // (16,64,4)
    const int*   labels = (const int*)d_in[4];     // (16,64)
    float4* ws4 = (float4*)d_ws;                   // NBLK float4 partials (32 KB)

    fused_kernel<<<NBLK, 256, 0, stream>>>(cp, whp, ofp, boxes, labels, ws4);
    finalize_kernel<<<1, 256, 0, stream>>>(ws4, (float*)d_out);
}